// Round 1
// baseline (1474.143 us; speedup 1.0000x reference)
//
#include <hip/hip_runtime.h>
#include <hip/hip_bf16.h>
#include <stdint.h>

#define M_DIM 8192
#define N_DIM 11008
#define K_DIM 4096

typedef __attribute__((ext_vector_type(8))) short bf16x8;
typedef __attribute__((ext_vector_type(4))) float f32x4;

// ---------------- FP4 code table (bitsandbytes), fp32-exact ----------------
__device__ const float kCodes[16] = {
    -1.0f, -(float)(2.0 / 3.0), -0.5f, -(float)(1.0 / 3.0), -0.25f,
    -(float)(1.0 / 6.0), -0.0052083333f, -0.0f,
    0.0f, 0.0052083333f, (float)(1.0 / 6.0), 0.25f,
    (float)(1.0 / 3.0), 0.5f, (float)(2.0 / 3.0), 1.0f};

__device__ __forceinline__ float fp4_bound(int i) {
  return (kCodes[i] + kCodes[i + 1]) * 0.5f;
}

__device__ __forceinline__ unsigned short f2bf(float f) {
  uint32_t u = __float_as_uint(f);
  u = (u + 0x7FFFu + ((u >> 16) & 1u)) >> 16;
  return (unsigned short)u;
}

// w -> nearest fp4 code * absmax (matches jnp.searchsorted side='left' on bounds)
__device__ __forceinline__ float fp4_rt(float w, float d, float am) {
  float n = w / d;
  int idx = 0;
#pragma unroll
  for (int i = 0; i < 15; ++i) idx += (n > fp4_bound(i)) ? 1 : 0;
  return kCodes[idx] * am;
}

// ---------------- Kernel 1: quantize->dequantize weight to bf16 ----------------
// each thread: 4 contiguous elems (float4); 16 lanes = one 64-elem block
__global__ void quant_fp4_kernel(const float* __restrict__ W,
                                 unsigned short* __restrict__ Wq) {
  int t = blockIdx.x * 256 + threadIdx.x;
  size_t base = (size_t)t * 4;
  float4 v = *reinterpret_cast<const float4*>(W + base);
  float am = fmaxf(fmaxf(fabsf(v.x), fabsf(v.y)), fmaxf(fabsf(v.z), fabsf(v.w)));
  am = fmaxf(am, __shfl_xor(am, 1));
  am = fmaxf(am, __shfl_xor(am, 2));
  am = fmaxf(am, __shfl_xor(am, 4));
  am = fmaxf(am, __shfl_xor(am, 8));
  float d = fmaxf(am, 1e-12f);
  ushort4 o;
  o.x = f2bf(fp4_rt(v.x, d, am));
  o.y = f2bf(fp4_rt(v.y, d, am));
  o.z = f2bf(fp4_rt(v.z, d, am));
  o.w = f2bf(fp4_rt(v.w, d, am));
  *reinterpret_cast<ushort4*>(Wq + base) = o;
}

// ---------------- Kernel 2: cast x fp32 -> bf16 ----------------
__device__ __forceinline__ uint32_t pack2(float lo, float hi) {
  return (uint32_t)f2bf(lo) | ((uint32_t)f2bf(hi) << 16);
}

__global__ void cast_bf16_kernel(const float* __restrict__ X,
                                 uint32_t* __restrict__ Y) {
  int t = blockIdx.x * 256 + threadIdx.x;
  size_t base = (size_t)t * 8;
  float4 a = *reinterpret_cast<const float4*>(X + base);
  float4 b = *reinterpret_cast<const float4*>(X + base + 4);
  uint4 o;
  o.x = pack2(a.x, a.y);
  o.y = pack2(a.z, a.w);
  o.z = pack2(b.x, b.y);
  o.w = pack2(b.z, b.w);
  *reinterpret_cast<uint4*>(Y + (size_t)t * 4) = o;
}

// ---------------- Kernel 3: bf16 GEMM, C = A[M,K] * B[N,K]^T + bias ----------------
// m97 structure: 128x128 tile, BK=32, 4 waves (2x2), each wave 64x64 out,
// global_load_lds width=16 staging, 2-barrier K-loop.
__device__ __forceinline__ void gload_lds16(const void* g, void* l) {
  __builtin_amdgcn_global_load_lds((const __attribute__((address_space(1))) void*)g,
                                   (__attribute__((address_space(3))) void*)l,
                                   16, 0, 0);
}

__global__ __launch_bounds__(256, 2) void gemm_bt_kernel(
    const short* __restrict__ A, const short* __restrict__ B,
    const float* __restrict__ bias, float* __restrict__ C) {
  __shared__ short Alds[128 * 32];
  __shared__ short Blds[128 * 32];

  const int tid = threadIdx.x;
  const int wave = tid >> 6;
  const int lane = tid & 63;
  const int wr = wave >> 1;  // wave row (0..1)
  const int wc = wave & 1;   // wave col (0..1)
  const int brow = blockIdx.y * 128;
  const int bcol = blockIdx.x * 128;

  // staging addressing: issue covers 64 rows; thread t -> row t/4, col (t&3)*8
  const int tr = tid >> 2;
  const int tc = (tid & 3) * 8;
  const short* Ag = A + (size_t)(brow + tr) * K_DIM + tc;
  const short* Bg = B + (size_t)(bcol + tr) * K_DIM + tc;

  short* AldsW = &Alds[wave * 512];  // wave-uniform base (lane*16B appended by HW)
  short* BldsW = &Blds[wave * 512];

  f32x4 acc[4][4] = {};

  // fragment read base: row = (lane&15), k = (lane>>4)*8, row stride 32 elems
  const int la = (lane & 15) * 32 + (lane >> 4) * 8;
  const short* Ar = &Alds[(wr * 64) * 32 + la];
  const short* Br = &Blds[(wc * 64) * 32 + la];

  for (int k0 = 0; k0 < K_DIM; k0 += 32) {
    gload_lds16(Ag, AldsW);
    gload_lds16(Ag + (size_t)64 * K_DIM, AldsW + 2048);
    gload_lds16(Bg, BldsW);
    gload_lds16(Bg + (size_t)64 * K_DIM, BldsW + 2048);
    __syncthreads();  // drains vmcnt -> staging complete

    bf16x8 af[4], bfr[4];
#pragma unroll
    for (int m = 0; m < 4; ++m)
      af[m] = *reinterpret_cast<const bf16x8*>(Ar + m * 16 * 32);
#pragma unroll
    for (int n = 0; n < 4; ++n)
      bfr[n] = *reinterpret_cast<const bf16x8*>(Br + n * 16 * 32);

#pragma unroll
    for (int m = 0; m < 4; ++m)
#pragma unroll
      for (int n = 0; n < 4; ++n)
        acc[m][n] =
            __builtin_amdgcn_mfma_f32_16x16x32_bf16(af[m], bfr[n], acc[m][n], 0, 0, 0);

    __syncthreads();  // all reads done before next overwrite
    Ag += 32;
    Bg += 32;
  }

  // epilogue: C/D layout col=lane&15, row=(lane>>4)*4+j  [m89-verified]
  const int crow0 = brow + wr * 64 + (lane >> 4) * 4;
  const int ccol0 = bcol + wc * 64 + (lane & 15);
#pragma unroll
  for (int n = 0; n < 4; ++n) {
    const int c = ccol0 + n * 16;
    const float bv = bias[c];
#pragma unroll
    for (int m = 0; m < 4; ++m) {
      const size_t rbase = (size_t)(crow0 + m * 16) * N_DIM + c;
#pragma unroll
      for (int j = 0; j < 4; ++j) C[rbase + (size_t)j * N_DIM] = acc[m][n][j] + bv;
    }
  }
}

extern "C" void kernel_launch(void* const* d_in, const int* in_sizes, int n_in,
                              void* d_out, int out_size, void* d_ws, size_t ws_size,
                              hipStream_t stream) {
  const float* x = (const float*)d_in[0];     // [8192, 4096]
  const float* w = (const float*)d_in[1];     // [11008, 4096]
  const float* bias = (const float*)d_in[2];  // [11008]
  float* out = (float*)d_out;                 // [8192, 11008]

  unsigned short* wq = (unsigned short*)d_ws;              // N*K bf16 = 90.2 MB
  unsigned short* xb = wq + (size_t)N_DIM * K_DIM;         // M*K bf16 = 67.1 MB

  {  // quantize->dequantize weight
    int nt = N_DIM * K_DIM / 4;  // 11,272,192 threads
    quant_fp4_kernel<<<nt / 256, 256, 0, stream>>>(w, wq);
  }
  {  // cast x
    int nt = M_DIM * K_DIM / 8;  // 4,194,304 threads
    cast_bf16_kernel<<<nt / 256, 256, 0, stream>>>(x, (uint32_t*)xb);
  }
  {
    dim3 grid(N_DIM / 128, M_DIM / 128);  // 86 x 64
    gemm_bt_kernel<<<grid, 256, 0, stream>>>((const short*)xb, (const short*)wq,
                                             bias, out);
  }
}

// Round 2
// 985.508 us; speedup vs baseline: 1.4958x; 1.4958x over previous
//
#include <hip/hip_runtime.h>
#include <hip/hip_bf16.h>
#include <stdint.h>

#define M_DIM 8192
#define N_DIM 11008
#define K_DIM 4096

typedef __attribute__((ext_vector_type(8))) short bf16x8;
typedef __attribute__((ext_vector_type(4))) float f32x4;

// ---------------- FP4 code table (bitsandbytes), fp32-exact ----------------
__device__ const float kCodes[16] = {
    -1.0f, -(float)(2.0 / 3.0), -0.5f, -(float)(1.0 / 3.0), -0.25f,
    -(float)(1.0 / 6.0), -0.0052083333f, -0.0f,
    0.0f, 0.0052083333f, (float)(1.0 / 6.0), 0.25f,
    (float)(1.0 / 3.0), 0.5f, (float)(2.0 / 3.0), 1.0f};

__device__ __forceinline__ float fp4_bound(int i) {
  return (kCodes[i] + kCodes[i + 1]) * 0.5f;
}

__device__ __forceinline__ unsigned short f2bf(float f) {
  uint32_t u = __float_as_uint(f);
  u = (u + 0x7FFFu + ((u >> 16) & 1u)) >> 16;
  return (unsigned short)u;
}

// w -> nearest fp4 code * absmax (matches jnp.searchsorted side='left' on bounds)
__device__ __forceinline__ float fp4_rt(float w, float d, float am) {
  float n = w / d;
  int idx = 0;
#pragma unroll
  for (int i = 0; i < 15; ++i) idx += (n > fp4_bound(i)) ? 1 : 0;
  return kCodes[idx] * am;
}

// ---------------- Kernel 1: quantize->dequantize weight to bf16 ----------------
// each thread: 4 contiguous elems (float4); 16 lanes = one 64-elem block
__global__ void quant_fp4_kernel(const float* __restrict__ W,
                                 unsigned short* __restrict__ Wq) {
  int t = blockIdx.x * 256 + threadIdx.x;
  size_t base = (size_t)t * 4;
  float4 v = *reinterpret_cast<const float4*>(W + base);
  float am = fmaxf(fmaxf(fabsf(v.x), fabsf(v.y)), fmaxf(fabsf(v.z), fabsf(v.w)));
  am = fmaxf(am, __shfl_xor(am, 1));
  am = fmaxf(am, __shfl_xor(am, 2));
  am = fmaxf(am, __shfl_xor(am, 4));
  am = fmaxf(am, __shfl_xor(am, 8));
  float d = fmaxf(am, 1e-12f);
  ushort4 o;
  o.x = f2bf(fp4_rt(v.x, d, am));
  o.y = f2bf(fp4_rt(v.y, d, am));
  o.z = f2bf(fp4_rt(v.z, d, am));
  o.w = f2bf(fp4_rt(v.w, d, am));
  *reinterpret_cast<ushort4*>(Wq + base) = o;
}

// ---------------- Kernel 2: cast x fp32 -> bf16 ----------------
__device__ __forceinline__ uint32_t pack2(float lo, float hi) {
  return (uint32_t)f2bf(lo) | ((uint32_t)f2bf(hi) << 16);
}

__global__ void cast_bf16_kernel(const float* __restrict__ X,
                                 uint32_t* __restrict__ Y) {
  int t = blockIdx.x * 256 + threadIdx.x;
  size_t base = (size_t)t * 8;
  float4 a = *reinterpret_cast<const float4*>(X + base);
  float4 b = *reinterpret_cast<const float4*>(X + base + 4);
  uint4 o;
  o.x = pack2(a.x, a.y);
  o.y = pack2(a.z, a.w);
  o.z = pack2(b.x, b.y);
  o.w = pack2(b.z, b.w);
  *reinterpret_cast<uint4*>(Y + (size_t)t * 4) = o;
}

// ---------------- Kernel 3: bf16 GEMM, C = A[M,K] * B[N,K]^T + bias ----------------
// m97 structure: 128x128 tile, BK=32, 4 waves (2x2), each wave 64x64 out,
// global_load_lds width=16 staging, 2-barrier K-loop.
// Grid: 1D, 5504 blocks; supertile + XCD-chunk decode:
//   XCD g = bid%8 owns row-group g (block-rows g*8..g*8+7), walks it
//   column-major (8 rows fast, 86 cols slow). Per group: A set = 8MB (L2/L3
//   hot), B streamed once, shared across XCDs via L3.
__device__ __forceinline__ void gload_lds16(const void* g, void* l) {
  __builtin_amdgcn_global_load_lds((const __attribute__((address_space(1))) void*)g,
                                   (__attribute__((address_space(3))) void*)l,
                                   16, 0, 0);
}

__global__ __launch_bounds__(256, 2) void gemm_bt_kernel(
    const short* __restrict__ A, const short* __restrict__ B,
    const float* __restrict__ bias, float* __restrict__ C) {
  __shared__ short Alds[128 * 32];
  __shared__ short Blds[128 * 32];

  const int tid = threadIdx.x;
  const int wave = tid >> 6;
  const int lane = tid & 63;
  const int wr = wave >> 1;  // wave row (0..1)
  const int wc = wave & 1;   // wave col (0..1)

  // supertile + XCD chunk decode
  const int bid = blockIdx.x;     // 0..5503
  const int g = bid & 7;          // XCD / row-group
  const int i = bid >> 3;         // 0..687 within group
  const int r = i & 7;            // row in group (fast)
  const int c = i >> 3;           // col (slow), 0..85
  const int brow = (g * 8 + r) * 128;
  const int bcol = c * 128;

  // staging addressing: issue covers 64 rows; thread t -> row t/4, col (t&3)*8
  const int tr = tid >> 2;
  const int tc = (tid & 3) * 8;
  const short* Ag = A + (size_t)(brow + tr) * K_DIM + tc;
  const short* Bg = B + (size_t)(bcol + tr) * K_DIM + tc;

  short* AldsW = &Alds[wave * 512];  // wave-uniform base (lane*16B appended by HW)
  short* BldsW = &Blds[wave * 512];

  f32x4 acc[4][4] = {};

  // fragment read base: row = (lane&15), k = (lane>>4)*8, row stride 32 elems
  const int la = (lane & 15) * 32 + (lane >> 4) * 8;
  const short* Ar = &Alds[(wr * 64) * 32 + la];
  const short* Br = &Blds[(wc * 64) * 32 + la];

  for (int k0 = 0; k0 < K_DIM; k0 += 32) {
    gload_lds16(Ag, AldsW);
    gload_lds16(Ag + (size_t)64 * K_DIM, AldsW + 2048);
    gload_lds16(Bg, BldsW);
    gload_lds16(Bg + (size_t)64 * K_DIM, BldsW + 2048);
    __syncthreads();  // drains vmcnt -> staging complete

    bf16x8 af[4], bfr[4];
#pragma unroll
    for (int m = 0; m < 4; ++m)
      af[m] = *reinterpret_cast<const bf16x8*>(Ar + m * 16 * 32);
#pragma unroll
    for (int n = 0; n < 4; ++n)
      bfr[n] = *reinterpret_cast<const bf16x8*>(Br + n * 16 * 32);

#pragma unroll
    for (int m = 0; m < 4; ++m)
#pragma unroll
      for (int n = 0; n < 4; ++n)
        acc[m][n] =
            __builtin_amdgcn_mfma_f32_16x16x32_bf16(af[m], bfr[n], acc[m][n], 0, 0, 0);

    __syncthreads();  // all reads done before next overwrite
    Ag += 32;
    Bg += 32;
  }

  // epilogue: C/D layout col=lane&15, row=(lane>>4)*4+j  [m89-verified]
  const int crow0 = brow + wr * 64 + (lane >> 4) * 4;
  const int ccol0 = bcol + wc * 64 + (lane & 15);
#pragma unroll
  for (int n = 0; n < 4; ++n) {
    const int cc = ccol0 + n * 16;
    const float bv = bias[cc];
#pragma unroll
    for (int m = 0; m < 4; ++m) {
      const size_t rbase = (size_t)(crow0 + m * 16) * N_DIM + cc;
#pragma unroll
      for (int j = 0; j < 4; ++j) C[rbase + (size_t)j * N_DIM] = acc[m][n][j] + bv;
    }
  }
}

extern "C" void kernel_launch(void* const* d_in, const int* in_sizes, int n_in,
                              void* d_out, int out_size, void* d_ws, size_t ws_size,
                              hipStream_t stream) {
  const float* x = (const float*)d_in[0];     // [8192, 4096]
  const float* w = (const float*)d_in[1];     // [11008, 4096]
  const float* bias = (const float*)d_in[2];  // [11008]
  float* out = (float*)d_out;                 // [8192, 11008]

  unsigned short* wq = (unsigned short*)d_ws;              // N*K bf16 = 90.2 MB
  unsigned short* xb = wq + (size_t)N_DIM * K_DIM;         // M*K bf16 = 67.1 MB

  {  // quantize->dequantize weight
    int nt = N_DIM * K_DIM / 4;  // 11,272,192 threads
    quant_fp4_kernel<<<nt / 256, 256, 0, stream>>>(w, wq);
  }
  {  // cast x
    int nt = M_DIM * K_DIM / 8;  // 4,194,304 threads
    cast_bf16_kernel<<<nt / 256, 256, 0, stream>>>(x, (uint32_t*)xb);
  }
  {
    // 1D grid: 8 groups x (8 rows x 86 cols) = 5504 blocks
    gemm_bt_kernel<<<dim3(5504), 256, 0, stream>>>((const short*)xb,
                                                   (const short*)wq, bias, out);
  }
}

// Round 3
// 792.952 us; speedup vs baseline: 1.8591x; 1.2428x over previous
//
#include <hip/hip_runtime.h>
#include <hip/hip_bf16.h>
#include <stdint.h>

#define M_DIM 8192
#define N_DIM 11008
#define K_DIM 4096

typedef __attribute__((ext_vector_type(8))) short bf16x8;
typedef __attribute__((ext_vector_type(4))) float f32x4;

// ---------------- FP4 code table (bitsandbytes), fp32-exact ----------------
__device__ const float kCodes[16] = {
    -1.0f, -(float)(2.0 / 3.0), -0.5f, -(float)(1.0 / 3.0), -0.25f,
    -(float)(1.0 / 6.0), -0.0052083333f, -0.0f,
    0.0f, 0.0052083333f, (float)(1.0 / 6.0), 0.25f,
    (float)(1.0 / 3.0), 0.5f, (float)(2.0 / 3.0), 1.0f};

__device__ __forceinline__ float fp4_bound(int i) {
  return (kCodes[i] + kCodes[i + 1]) * 0.5f;
}

__device__ __forceinline__ unsigned short f2bf(float f) {
  uint32_t u = __float_as_uint(f);
  u = (u + 0x7FFFu + ((u >> 16) & 1u)) >> 16;
  return (unsigned short)u;
}

__device__ __forceinline__ float fp4_rt(float w, float d, float am) {
  float n = w / d;
  int idx = 0;
#pragma unroll
  for (int i = 0; i < 15; ++i) idx += (n > fp4_bound(i)) ? 1 : 0;
  return kCodes[idx] * am;
}

// ---------------- Kernel 1: quantize->dequantize weight to bf16 ----------------
__global__ void quant_fp4_kernel(const float* __restrict__ W,
                                 unsigned short* __restrict__ Wq) {
  int t = blockIdx.x * 256 + threadIdx.x;
  size_t base = (size_t)t * 4;
  float4 v = *reinterpret_cast<const float4*>(W + base);
  float am = fmaxf(fmaxf(fabsf(v.x), fabsf(v.y)), fmaxf(fabsf(v.z), fabsf(v.w)));
  am = fmaxf(am, __shfl_xor(am, 1));
  am = fmaxf(am, __shfl_xor(am, 2));
  am = fmaxf(am, __shfl_xor(am, 4));
  am = fmaxf(am, __shfl_xor(am, 8));
  float d = fmaxf(am, 1e-12f);
  ushort4 o;
  o.x = f2bf(fp4_rt(v.x, d, am));
  o.y = f2bf(fp4_rt(v.y, d, am));
  o.z = f2bf(fp4_rt(v.z, d, am));
  o.w = f2bf(fp4_rt(v.w, d, am));
  *reinterpret_cast<ushort4*>(Wq + base) = o;
}

// ---------------- Kernel 2: cast x fp32 -> bf16 ----------------
__device__ __forceinline__ uint32_t pack2(float lo, float hi) {
  return (uint32_t)f2bf(lo) | ((uint32_t)f2bf(hi) << 16);
}

__global__ void cast_bf16_kernel(const float* __restrict__ X,
                                 uint32_t* __restrict__ Y) {
  int t = blockIdx.x * 256 + threadIdx.x;
  size_t base = (size_t)t * 8;
  float4 a = *reinterpret_cast<const float4*>(X + base);
  float4 b = *reinterpret_cast<const float4*>(X + base + 4);
  uint4 o;
  o.x = pack2(a.x, a.y);
  o.y = pack2(a.z, a.w);
  o.z = pack2(b.x, b.y);
  o.w = pack2(b.z, b.w);
  *reinterpret_cast<uint4*>(Y + (size_t)t * 4) = o;
}

// ---------------- Kernel 3: 256x256 8-phase bf16 GEMM (m201 template) -------
// C[M,N] = A[M,K] * B[N,K]^T + bias.  BM=BN=256, BK=64, 512 thr = 8 waves
// (2M x 4N), acc[8][4] f32x4/wave.  LDS 128KB: [2 dbuf][A0,A1,B0,B1][16KB].
// st_16x32 swizzle: lds_byte = logical_byte ^ ((bit9)<<5); staging keeps the
// LDS dest linear and pre-swizzles the per-lane GLOBAL source (rule #21).
// vmcnt(4) only at phases 3/7; lgkmcnt(0)+sched_barrier before each MFMA
// cluster; s_setprio(1) around MFMA (T5).
#define GLOAD(src, dst)                                                        \
  __builtin_amdgcn_global_load_lds(                                           \
      (const __attribute__((address_space(1))) void*)(src),                   \
      (__attribute__((address_space(3))) void*)(dst), 16, 0, 0)

#define PHASE_MID()                                                            \
  __builtin_amdgcn_s_barrier();                                                \
  asm volatile("s_waitcnt lgkmcnt(0)" ::: "memory");                           \
  __builtin_amdgcn_sched_barrier(0);                                           \
  __builtin_amdgcn_s_setprio(1);

#define PHASE_END()                                                            \
  __builtin_amdgcn_s_setprio(0);                                               \
  __builtin_amdgcn_sched_barrier(0);                                           \
  __builtin_amdgcn_s_barrier();

#define PHASE_END_VM()                                                         \
  __builtin_amdgcn_s_setprio(0);                                               \
  __builtin_amdgcn_sched_barrier(0);                                           \
  asm volatile("s_waitcnt vmcnt(4)" ::: "memory");                             \
  __builtin_amdgcn_s_barrier();

__global__ __launch_bounds__(512, 2) void gemm256_kernel(
    const short* __restrict__ A, const short* __restrict__ B,
    const float* __restrict__ bias, float* __restrict__ C) {
  __shared__ short lds[2][4][8192];  // [buf][A0,A1,B0,B1][16KB half]

  const int tid = threadIdx.x;
  const int wave = tid >> 6;
  const int lane = tid & 63;
  const int l15 = lane & 15;
  const int q4 = lane >> 4;
  const int wm = wave >> 2;  // 0..1
  const int wn = wave & 3;   // 0..3

  // XCD-chunked swizzle: 1376 blocks = 8 XCDs x 172; XCD g owns M-rows
  // [g*4, g*4+4) x all 43 N-cols, walked 4-rows-fast (A panel 8MB L2-hot).
  const int bid = blockIdx.x;
  const int g = bid & 7;
  const int idx = bid >> 3;  // 0..171
  const int brow = (g * 4 + (idx & 3)) * 256;
  const int bcol = (idx >> 2) * 256;

  // ---- staging source (pre-swizzled global addr; linear LDS dest) ----
  // chunk q = tid (rows 0-63 of a half) and q+512 (rows 64-127, = +64*K)
  const int lp = (tid * 16) ^ (((tid >> 5) & 1) << 5);
  const int srow = lp >> 7;          // 0..63
  const int scol = (lp & 127) >> 1;  // element col, multiple of 8
  const short* Asrc = A + (size_t)(brow + srow) * K_DIM + scol;
  const short* Bsrc = B + (size_t)(bcol + srow) * K_DIM + scol;
  const int wu0 = wave * 512;         // wave-uniform LDS short-offset, chunk0
  const int wu1 = 4096 + wave * 512;  // chunk1

  auto stageA = [&](int buf, int half, int t) {
    const short* s = Asrc + (size_t)half * 128 * K_DIM + t * 64;
    GLOAD(s, &lds[buf][half][wu0]);
    GLOAD(s + (size_t)64 * K_DIM, &lds[buf][half][wu1]);
  };
  auto stageB = [&](int buf, int half, int t) {
    const short* s = Bsrc + (size_t)half * 128 * K_DIM + t * 64;
    GLOAD(s, &lds[buf][2 + half][wu0]);
    GLOAD(s + (size_t)64 * K_DIM, &lds[buf][2 + half][wu1]);
  };

  // ---- fragment read bases (swizzled) ----
  // A frag (m,kk): byte = (m*16+l15)*128 + ((kk*64 + q4*16) ^ ((l15&4)<<3))
  const int offk0 = (q4 * 16) ^ ((l15 & 4) << 3);
  const int offk1 = offk0 + 64;
  const char* aP[2] = {(const char*)&lds[0][wm][0] + l15 * 128,
                       (const char*)&lds[1][wm][0] + l15 * 128};
  const char* bP[2] = {
      (const char*)&lds[0][2 + (wn >> 1)][0] + (wn & 1) * 8192 + l15 * 128,
      (const char*)&lds[1][2 + (wn >> 1)][0] + (wn & 1) * 8192 + l15 * 128};

  f32x4 acc[8][4] = {};

  // ---- prologue: stage T0 fully + T1 B-halves; wait T0 landed ----
  stageB(0, 0, 0);
  stageB(0, 1, 0);
  stageA(0, 0, 0);
  stageA(0, 1, 0);
  stageB(1, 0, 1);
  stageB(1, 1, 1);
  asm volatile("s_waitcnt vmcnt(4)" ::: "memory");  // T0's 4 halves landed
  __builtin_amdgcn_s_barrier();

  for (int i = 0; i < 32; ++i) {
    const int t1 = 2 * i + 1;
    const int t2 = (2 * i + 2 < 64) ? 2 * i + 2 : 63;  // clamped (tail: data unused)
    const int t3 = (2 * i + 3 < 64) ? 2 * i + 3 : 63;

    bf16x8 af[4], bf[2][4];

    // ===== phases 0-3: compute buf0 (tile 2i) =====
    // ph0: A kk0 m0-3 + all B; stage T1.A0 -> buf1
#pragma unroll
    for (int m = 0; m < 4; ++m)
      af[m] = *(const bf16x8*)(aP[0] + m * 2048 + offk0);
#pragma unroll
    for (int n = 0; n < 4; ++n)
      bf[0][n] = *(const bf16x8*)(bP[0] + n * 2048 + offk0);
#pragma unroll
    for (int n = 0; n < 4; ++n)
      bf[1][n] = *(const bf16x8*)(bP[0] + n * 2048 + offk1);
    stageA(1, 0, t1);
    PHASE_MID();
#pragma unroll
    for (int m = 0; m < 4; ++m)
#pragma unroll
      for (int n = 0; n < 4; ++n)
        acc[m][n] = __builtin_amdgcn_mfma_f32_16x16x32_bf16(af[m], bf[0][n],
                                                            acc[m][n], 0, 0, 0);
    PHASE_END();

    // ph1: A kk0 m4-7; stage T1.A1 -> buf1
#pragma unroll
    for (int m = 0; m < 4; ++m)
      af[m] = *(const bf16x8*)(aP[0] + (4 + m) * 2048 + offk0);
    stageA(1, 1, t1);
    PHASE_MID();
#pragma unroll
    for (int m = 0; m < 4; ++m)
#pragma unroll
      for (int n = 0; n < 4; ++n)
        acc[4 + m][n] = __builtin_amdgcn_mfma_f32_16x16x32_bf16(
            af[m], bf[0][n], acc[4 + m][n], 0, 0, 0);
    PHASE_END();

    // ph2: A kk1 m0-3; stage T2.B0 -> buf0 (B halves free after ph0 drain+ph1 bar)
#pragma unroll
    for (int m = 0; m < 4; ++m)
      af[m] = *(const bf16x8*)(aP[0] + m * 2048 + offk1);
    stageB(0, 0, t2);
    PHASE_MID();
#pragma unroll
    for (int m = 0; m < 4; ++m)
#pragma unroll
      for (int n = 0; n < 4; ++n)
        acc[m][n] = __builtin_amdgcn_mfma_f32_16x16x32_bf16(af[m], bf[1][n],
                                                            acc[m][n], 0, 0, 0);
    PHASE_END();

    // ph3: A kk1 m4-7; stage T2.B1 -> buf0; vmcnt(4): buf1's 4 halves landed
#pragma unroll
    for (int m = 0; m < 4; ++m)
      af[m] = *(const bf16x8*)(aP[0] + (4 + m) * 2048 + offk1);
    stageB(0, 1, t2);
    PHASE_MID();
#pragma unroll
    for (int m = 0; m < 4; ++m)
#pragma unroll
      for (int n = 0; n < 4; ++n)
        acc[4 + m][n] = __builtin_amdgcn_mfma_f32_16x16x32_bf16(
            af[m], bf[1][n], acc[4 + m][n], 0, 0, 0);
    PHASE_END_VM();

    // ===== phases 4-7: compute buf1 (tile 2i+1) =====
    // ph4: A kk0 m0-3 + all B; stage T2.A0 -> buf0
#pragma unroll
    for (int m = 0; m < 4; ++m)
      af[m] = *(const bf16x8*)(aP[1] + m * 2048 + offk0);
#pragma unroll
    for (int n = 0; n < 4; ++n)
      bf[0][n] = *(const bf16x8*)(bP[1] + n * 2048 + offk0);
#pragma unroll
    for (int n = 0; n < 4; ++n)
      bf[1][n] = *(const bf16x8*)(bP[1] + n * 2048 + offk1);
    stageA(0, 0, t2);
    PHASE_MID();
#pragma unroll
    for (int m = 0; m < 4; ++m)
#pragma unroll
      for (int n = 0; n < 4; ++n)
        acc[m][n] = __builtin_amdgcn_mfma_f32_16x16x32_bf16(af[m], bf[0][n],
                                                            acc[m][n], 0, 0, 0);
    PHASE_END();

    // ph5: A kk0 m4-7; stage T2.A1 -> buf0
#pragma unroll
    for (int m = 0; m < 4; ++m)
      af[m] = *(const bf16x8*)(aP[1] + (4 + m) * 2048 + offk0);
    stageA(0, 1, t2);
    PHASE_MID();
#pragma unroll
    for (int m = 0; m < 4; ++m)
#pragma unroll
      for (int n = 0; n < 4; ++n)
        acc[4 + m][n] = __builtin_amdgcn_mfma_f32_16x16x32_bf16(
            af[m], bf[0][n], acc[4 + m][n], 0, 0, 0);
    PHASE_END();

    // ph6: A kk1 m0-3; stage T3.B0 -> buf1
#pragma unroll
    for (int m = 0; m < 4; ++m)
      af[m] = *(const bf16x8*)(aP[1] + m * 2048 + offk1);
    stageB(1, 0, t3);
    PHASE_MID();
#pragma unroll
    for (int m = 0; m < 4; ++m)
#pragma unroll
      for (int n = 0; n < 4; ++n)
        acc[m][n] = __builtin_amdgcn_mfma_f32_16x16x32_bf16(af[m], bf[1][n],
                                                            acc[m][n], 0, 0, 0);
    PHASE_END();

    // ph7: A kk1 m4-7; stage T3.B1 -> buf1; vmcnt(4): buf0's 4 halves landed
#pragma unroll
    for (int m = 0; m < 4; ++m)
      af[m] = *(const bf16x8*)(aP[1] + (4 + m) * 2048 + offk1);
    stageB(1, 1, t3);
    PHASE_MID();
#pragma unroll
    for (int m = 0; m < 4; ++m)
#pragma unroll
      for (int n = 0; n < 4; ++n)
        acc[4 + m][n] = __builtin_amdgcn_mfma_f32_16x16x32_bf16(
            af[m], bf[1][n], acc[4 + m][n], 0, 0, 0);
    PHASE_END_VM();
  }

  // ---- epilogue: C/D layout col=lane&15, row=(lane>>4)*4+j ----
  const int crow0 = brow + wm * 128 + q4 * 4;
  const int ccol0 = bcol + wn * 64 + l15;
#pragma unroll
  for (int n = 0; n < 4; ++n) {
    const float bv = bias[ccol0 + n * 16];
#pragma unroll
    for (int m = 0; m < 8; ++m) {
      const size_t rb = (size_t)(crow0 + m * 16) * N_DIM + (ccol0 + n * 16);
#pragma unroll
      for (int j = 0; j < 4; ++j) C[rb + (size_t)j * N_DIM] = acc[m][n][j] + bv;
    }
  }
}

extern "C" void kernel_launch(void* const* d_in, const int* in_sizes, int n_in,
                              void* d_out, int out_size, void* d_ws, size_t ws_size,
                              hipStream_t stream) {
  const float* x = (const float*)d_in[0];     // [8192, 4096]
  const float* w = (const float*)d_in[1];     // [11008, 4096]
  const float* bias = (const float*)d_in[2];  // [11008]
  float* out = (float*)d_out;                 // [8192, 11008]

  unsigned short* wq = (unsigned short*)d_ws;       // N*K bf16
  unsigned short* xb = wq + (size_t)N_DIM * K_DIM;  // M*K bf16

  {
    int nt = N_DIM * K_DIM / 4;
    quant_fp4_kernel<<<nt / 256, 256, 0, stream>>>(w, wq);
  }
  {
    int nt = M_DIM * K_DIM / 8;
    cast_bf16_kernel<<<nt / 256, 256, 0, stream>>>(x, (uint32_t*)xb);
  }
  {
    // 1376 = (8192/256) * (11008/256) = 8 XCD-chunks x 172
    gemm256_kernel<<<dim3(1376), 512, 0, stream>>>((const short*)xb,
                                                   (const short*)wq, bias, out);
  }
}

// Round 4
// 751.674 us; speedup vs baseline: 1.9611x; 1.0549x over previous
//
#include <hip/hip_runtime.h>
#include <hip/hip_bf16.h>
#include <stdint.h>

#define M_DIM 8192
#define N_DIM 11008
#define K_DIM 4096

typedef __attribute__((ext_vector_type(8))) short bf16x8;
typedef __attribute__((ext_vector_type(4))) float f32x4;

// ---------------- FP4 code table (bitsandbytes), fp32-exact ----------------
__device__ const float kCodes[16] = {
    -1.0f, -(float)(2.0 / 3.0), -0.5f, -(float)(1.0 / 3.0), -0.25f,
    -(float)(1.0 / 6.0), -0.0052083333f, -0.0f,
    0.0f, 0.0052083333f, (float)(1.0 / 6.0), 0.25f,
    (float)(1.0 / 3.0), 0.5f, (float)(2.0 / 3.0), 1.0f};

__device__ __forceinline__ float fp4_bound(int i) {
  return (kCodes[i] + kCodes[i + 1]) * 0.5f;
}

__device__ __forceinline__ unsigned short f2bf(float f) {
  uint32_t u = __float_as_uint(f);
  u = (u + 0x7FFFu + ((u >> 16) & 1u)) >> 16;
  return (unsigned short)u;
}

__device__ __forceinline__ float fp4_rt(float w, float d, float am) {
  float n = w / d;
  int idx = 0;
#pragma unroll
  for (int i = 0; i < 15; ++i) idx += (n > fp4_bound(i)) ? 1 : 0;
  return kCodes[idx] * am;
}

// ---------------- Kernel 1: quantize->dequantize weight to bf16 ----------------
__global__ void quant_fp4_kernel(const float* __restrict__ W,
                                 unsigned short* __restrict__ Wq) {
  int t = blockIdx.x * 256 + threadIdx.x;
  size_t base = (size_t)t * 4;
  float4 v = *reinterpret_cast<const float4*>(W + base);
  float am = fmaxf(fmaxf(fabsf(v.x), fabsf(v.y)), fmaxf(fabsf(v.z), fabsf(v.w)));
  am = fmaxf(am, __shfl_xor(am, 1));
  am = fmaxf(am, __shfl_xor(am, 2));
  am = fmaxf(am, __shfl_xor(am, 4));
  am = fmaxf(am, __shfl_xor(am, 8));
  float d = fmaxf(am, 1e-12f);
  ushort4 o;
  o.x = f2bf(fp4_rt(v.x, d, am));
  o.y = f2bf(fp4_rt(v.y, d, am));
  o.z = f2bf(fp4_rt(v.z, d, am));
  o.w = f2bf(fp4_rt(v.w, d, am));
  *reinterpret_cast<ushort4*>(Wq + base) = o;
}

// ---------------- Kernel 2: cast x fp32 -> bf16 ----------------
__device__ __forceinline__ uint32_t pack2(float lo, float hi) {
  return (uint32_t)f2bf(lo) | ((uint32_t)f2bf(hi) << 16);
}

__global__ void cast_bf16_kernel(const float* __restrict__ X,
                                 uint32_t* __restrict__ Y) {
  int t = blockIdx.x * 256 + threadIdx.x;
  size_t base = (size_t)t * 8;
  float4 a = *reinterpret_cast<const float4*>(X + base);
  float4 b = *reinterpret_cast<const float4*>(X + base + 4);
  uint4 o;
  o.x = pack2(a.x, a.y);
  o.y = pack2(a.z, a.w);
  o.z = pack2(b.x, b.y);
  o.w = pack2(b.z, b.w);
  *reinterpret_cast<uint4*>(Y + (size_t)t * 4) = o;
}

// ---------------- Kernel 3: 256x256 8-phase bf16 GEMM (m201 template) -------
// C[M,N] = A[M,K] * B[N,K]^T + bias.  BM=BN=256, BK=64, 512 thr = 8 waves
// (2M x 4N), acc[8][4] f32x4/wave.  LDS 128KB: [2 dbuf][A0,A1,B0,B1][16KB].
// Full 3-bit swizzle: phys_byte = row*128 + (colbyte ^ ((row&7)<<4)).
// Per ds_read_b128 the 64 lanes' nibble index = q4 ^ (l15&7) (^4kk) ->
// every 16B slot {0..112} hit exactly 8x -> all 32 banks, min 8 cycles.
// Staging keeps LDS dest LINEAR and inverse-swizzles the GLOBAL source
// (both-sides-or-neither, rule #21).
#define GLOAD(src, dst)                                                        \
  __builtin_amdgcn_global_load_lds(                                           \
      (const __attribute__((address_space(1))) void*)(src),                   \
      (__attribute__((address_space(3))) void*)(dst), 16, 0, 0)

#define PHASE_MID()                                                            \
  __builtin_amdgcn_s_barrier();                                                \
  asm volatile("s_waitcnt lgkmcnt(0)" ::: "memory");                           \
  __builtin_amdgcn_sched_barrier(0);                                           \
  __builtin_amdgcn_s_setprio(1);

#define PHASE_END()                                                            \
  __builtin_amdgcn_s_setprio(0);                                               \
  __builtin_amdgcn_sched_barrier(0);                                           \
  __builtin_amdgcn_s_barrier();

#define PHASE_END_VM()                                                         \
  __builtin_amdgcn_s_setprio(0);                                               \
  __builtin_amdgcn_sched_barrier(0);                                           \
  asm volatile("s_waitcnt vmcnt(4)" ::: "memory");                             \
  __builtin_amdgcn_s_barrier();

__global__ __launch_bounds__(512, 2) void gemm256_kernel(
    const short* __restrict__ A, const short* __restrict__ B,
    const float* __restrict__ bias, float* __restrict__ C) {
  __shared__ short lds[2][4][8192];  // [buf][A0,A1,B0,B1][16KB half]

  const int tid = threadIdx.x;
  const int wave = tid >> 6;
  const int lane = tid & 63;
  const int l15 = lane & 15;
  const int q4 = lane >> 4;
  const int wm = wave >> 2;  // 0..1
  const int wn = wave & 3;   // 0..3

  // XCD-chunked swizzle: 1376 blocks = 8 XCDs x 172; XCD g owns M-rows
  // [g*4, g*4+4) x all 43 N-cols, walked 4-rows-fast (A panel 8MB L2-hot).
  const int bid = blockIdx.x;
  const int g = bid & 7;
  const int idx = bid >> 3;  // 0..171
  const int brow = (g * 4 + (idx & 3)) * 256;
  const int bcol = (idx >> 2) * 256;

  // ---- staging source (inverse-swizzled global addr; linear LDS dest) ----
  // thread t writes phys bytes [t*16, t*16+16) of a half-chunk:
  //   phys row = t>>3, phys nibble = t&7 -> logical nibble = (t&7)^((t>>3)&7)
  const int srow = tid >> 3;                               // 0..63
  const int scol = ((tid & 7) ^ ((tid >> 3) & 7)) << 3;    // element col
  const short* Asrc = A + (size_t)(brow + srow) * K_DIM + scol;
  const short* Bsrc = B + (size_t)(bcol + srow) * K_DIM + scol;
  const int wu0 = wave * 512;         // wave-uniform LDS short-offset, chunk0
  const int wu1 = 4096 + wave * 512;  // chunk1 (rows 64-127; (row&7) unchanged)

  auto stageA = [&](int buf, int half, int t) {
    const short* s = Asrc + (size_t)half * 128 * K_DIM + t * 64;
    GLOAD(s, &lds[buf][half][wu0]);
    GLOAD(s + (size_t)64 * K_DIM, &lds[buf][half][wu1]);
  };
  auto stageB = [&](int buf, int half, int t) {
    const short* s = Bsrc + (size_t)half * 128 * K_DIM + t * 64;
    GLOAD(s, &lds[buf][2 + half][wu0]);
    GLOAD(s + (size_t)64 * K_DIM, &lds[buf][2 + half][wu1]);
  };

  // ---- fragment read bases (swizzled) ----
  // frag (m,kk): phys byte = (m*16+l15)*128 + (((kk<<2|q4) ^ (l15&7)) << 4)
  const int offk0 = ((q4 ^ (l15 & 7)) << 4);
  const int offk1 = offk0 ^ 64;
  const char* aP[2] = {(const char*)&lds[0][wm][0] + l15 * 128,
                       (const char*)&lds[1][wm][0] + l15 * 128};
  const char* bP[2] = {
      (const char*)&lds[0][2 + (wn >> 1)][0] + (wn & 1) * 8192 + l15 * 128,
      (const char*)&lds[1][2 + (wn >> 1)][0] + (wn & 1) * 8192 + l15 * 128};

  f32x4 acc[8][4] = {};

  // ---- prologue: stage T0 fully + T1 B-halves; wait T0 landed ----
  stageB(0, 0, 0);
  stageB(0, 1, 0);
  stageA(0, 0, 0);
  stageA(0, 1, 0);
  stageB(1, 0, 1);
  stageB(1, 1, 1);
  asm volatile("s_waitcnt vmcnt(4)" ::: "memory");  // T0's 4 halves landed
  __builtin_amdgcn_s_barrier();

  for (int i = 0; i < 32; ++i) {
    const int t1 = 2 * i + 1;
    const int t2 = (2 * i + 2 < 64) ? 2 * i + 2 : 63;  // clamped (tail: data unused)
    const int t3 = (2 * i + 3 < 64) ? 2 * i + 3 : 63;

    bf16x8 af[4], bf[2][4];

    // ===== phases 0-3: compute buf0 (tile 2i) =====
    // ph0: A kk0 m0-3 + all B; stage T1.A0 -> buf1
#pragma unroll
    for (int m = 0; m < 4; ++m)
      af[m] = *(const bf16x8*)(aP[0] + m * 2048 + offk0);
#pragma unroll
    for (int n = 0; n < 4; ++n)
      bf[0][n] = *(const bf16x8*)(bP[0] + n * 2048 + offk0);
#pragma unroll
    for (int n = 0; n < 4; ++n)
      bf[1][n] = *(const bf16x8*)(bP[0] + n * 2048 + offk1);
    stageA(1, 0, t1);
    PHASE_MID();
#pragma unroll
    for (int m = 0; m < 4; ++m)
#pragma unroll
      for (int n = 0; n < 4; ++n)
        acc[m][n] = __builtin_amdgcn_mfma_f32_16x16x32_bf16(af[m], bf[0][n],
                                                            acc[m][n], 0, 0, 0);
    PHASE_END();

    // ph1: A kk0 m4-7; stage T1.A1 -> buf1
#pragma unroll
    for (int m = 0; m < 4; ++m)
      af[m] = *(const bf16x8*)(aP[0] + (4 + m) * 2048 + offk0);
    stageA(1, 1, t1);
    PHASE_MID();
#pragma unroll
    for (int m = 0; m < 4; ++m)
#pragma unroll
      for (int n = 0; n < 4; ++n)
        acc[4 + m][n] = __builtin_amdgcn_mfma_f32_16x16x32_bf16(
            af[m], bf[0][n], acc[4 + m][n], 0, 0, 0);
    PHASE_END();

    // ph2: A kk1 m0-3; stage T2.B0 -> buf0 (B halves free after ph0 drain+ph1 bar)
#pragma unroll
    for (int m = 0; m < 4; ++m)
      af[m] = *(const bf16x8*)(aP[0] + m * 2048 + offk1);
    stageB(0, 0, t2);
    PHASE_MID();
#pragma unroll
    for (int m = 0; m < 4; ++m)
#pragma unroll
      for (int n = 0; n < 4; ++n)
        acc[m][n] = __builtin_amdgcn_mfma_f32_16x16x32_bf16(af[m], bf[1][n],
                                                            acc[m][n], 0, 0, 0);
    PHASE_END();

    // ph3: A kk1 m4-7; stage T2.B1 -> buf0; vmcnt(4): buf1's 4 halves landed
#pragma unroll
    for (int m = 0; m < 4; ++m)
      af[m] = *(const bf16x8*)(aP[0] + (4 + m) * 2048 + offk1);
    stageB(0, 1, t2);
    PHASE_MID();
#pragma unroll
    for (int m = 0; m < 4; ++m)
#pragma unroll
      for (int n = 0; n < 4; ++n)
        acc[4 + m][n] = __builtin_amdgcn_mfma_f32_16x16x32_bf16(
            af[m], bf[1][n], acc[4 + m][n], 0, 0, 0);
    PHASE_END_VM();

    // ===== phases 4-7: compute buf1 (tile 2i+1) =====
    // ph4: A kk0 m0-3 + all B; stage T2.A0 -> buf0
#pragma unroll
    for (int m = 0; m < 4; ++m)
      af[m] = *(const bf16x8*)(aP[1] + m * 2048 + offk0);
#pragma unroll
    for (int n = 0; n < 4; ++n)
      bf[0][n] = *(const bf16x8*)(bP[1] + n * 2048 + offk0);
#pragma unroll
    for (int n = 0; n < 4; ++n)
      bf[1][n] = *(const bf16x8*)(bP[1] + n * 2048 + offk1);
    stageA(0, 0, t2);
    PHASE_MID();
#pragma unroll
    for (int m = 0; m < 4; ++m)
#pragma unroll
      for (int n = 0; n < 4; ++n)
        acc[m][n] = __builtin_amdgcn_mfma_f32_16x16x32_bf16(af[m], bf[0][n],
                                                            acc[m][n], 0, 0, 0);
    PHASE_END();

    // ph5: A kk0 m4-7; stage T2.A1 -> buf0
#pragma unroll
    for (int m = 0; m < 4; ++m)
      af[m] = *(const bf16x8*)(aP[1] + (4 + m) * 2048 + offk0);
    stageA(0, 1, t2);
    PHASE_MID();
#pragma unroll
    for (int m = 0; m < 4; ++m)
#pragma unroll
      for (int n = 0; n < 4; ++n)
        acc[4 + m][n] = __builtin_amdgcn_mfma_f32_16x16x32_bf16(
            af[m], bf[0][n], acc[4 + m][n], 0, 0, 0);
    PHASE_END();

    // ph6: A kk1 m0-3; stage T3.B0 -> buf1
#pragma unroll
    for (int m = 0; m < 4; ++m)
      af[m] = *(const bf16x8*)(aP[1] + m * 2048 + offk1);
    stageB(1, 0, t3);
    PHASE_MID();
#pragma unroll
    for (int m = 0; m < 4; ++m)
#pragma unroll
      for (int n = 0; n < 4; ++n)
        acc[m][n] = __builtin_amdgcn_mfma_f32_16x16x32_bf16(af[m], bf[1][n],
                                                            acc[m][n], 0, 0, 0);
    PHASE_END();

    // ph7: A kk1 m4-7; stage T3.B1 -> buf1; vmcnt(4): buf0's 4 halves landed
#pragma unroll
    for (int m = 0; m < 4; ++m)
      af[m] = *(const bf16x8*)(aP[1] + (4 + m) * 2048 + offk1);
    stageB(1, 1, t3);
    PHASE_MID();
#pragma unroll
    for (int m = 0; m < 4; ++m)
#pragma unroll
      for (int n = 0; n < 4; ++n)
        acc[4 + m][n] = __builtin_amdgcn_mfma_f32_16x16x32_bf16(
            af[m], bf[1][n], acc[4 + m][n], 0, 0, 0);
    PHASE_END_VM();
  }

  // ---- epilogue: C/D layout col=lane&15, row=(lane>>4)*4+j ----
  const int crow0 = brow + wm * 128 + q4 * 4;
  const int ccol0 = bcol + wn * 64 + l15;
#pragma unroll
  for (int n = 0; n < 4; ++n) {
    const float bv = bias[ccol0 + n * 16];
#pragma unroll
    for (int m = 0; m < 8; ++m) {
      const size_t rb = (size_t)(crow0 + m * 16) * N_DIM + (ccol0 + n * 16);
#pragma unroll
      for (int j = 0; j < 4; ++j) C[rb + (size_t)j * N_DIM] = acc[m][n][j] + bv;
    }
  }
}

extern "C" void kernel_launch(void* const* d_in, const int* in_sizes, int n_in,
                              void* d_out, int out_size, void* d_ws, size_t ws_size,
                              hipStream_t stream) {
  const float* x = (const float*)d_in[0];     // [8192, 4096]
  const float* w = (const float*)d_in[1];     // [11008, 4096]
  const float* bias = (const float*)d_in[2];  // [11008]
  float* out = (float*)d_out;                 // [8192, 11008]

  unsigned short* wq = (unsigned short*)d_ws;       // N*K bf16
  unsigned short* xb = wq + (size_t)N_DIM * K_DIM;  // M*K bf16

  {
    int nt = N_DIM * K_DIM / 4;
    quant_fp4_kernel<<<nt / 256, 256, 0, stream>>>(w, wq);
  }
  {
    int nt = M_DIM * K_DIM / 8;
    cast_bf16_kernel<<<nt / 256, 256, 0, stream>>>(x, (uint32_t*)xb);
  }
  {
    // 1376 = (8192/256) * (11008/256) = 8 XCD-chunks x 172
    gemm256_kernel<<<dim3(1376), 512, 0, stream>>>((const short*)xb,
                                                   (const short*)wq, bias, out);
  }
}

// Round 5
// 750.548 us; speedup vs baseline: 1.9641x; 1.0015x over previous
//
#include <hip/hip_runtime.h>
#include <hip/hip_bf16.h>
#include <stdint.h>

#define M_DIM 8192
#define N_DIM 11008
#define K_DIM 4096

typedef __attribute__((ext_vector_type(8))) short bf16x8;
typedef __attribute__((ext_vector_type(4))) float f32x4;

// ---------------- FP4 code table (bitsandbytes), fp32-exact ----------------
__device__ const float kCodes[16] = {
    -1.0f, -(float)(2.0 / 3.0), -0.5f, -(float)(1.0 / 3.0), -0.25f,
    -(float)(1.0 / 6.0), -0.0052083333f, -0.0f,
    0.0f, 0.0052083333f, (float)(1.0 / 6.0), 0.25f,
    (float)(1.0 / 3.0), 0.5f, (float)(2.0 / 3.0), 1.0f};

__device__ __forceinline__ float fp4_bound(int i) {
  return (kCodes[i] + kCodes[i + 1]) * 0.5f;
}

__device__ __forceinline__ unsigned short f2bf(float f) {
  uint32_t u = __float_as_uint(f);
  u = (u + 0x7FFFu + ((u >> 16) & 1u)) >> 16;
  return (unsigned short)u;
}

__device__ __forceinline__ float fp4_rt(float w, float d, float am) {
  float n = w / d;
  int idx = 0;
#pragma unroll
  for (int i = 0; i < 15; ++i) idx += (n > fp4_bound(i)) ? 1 : 0;
  return kCodes[idx] * am;
}

// ---------------- Kernel 1: quantize->dequantize weight to bf16 ----------------
__global__ void quant_fp4_kernel(const float* __restrict__ W,
                                 unsigned short* __restrict__ Wq) {
  int t = blockIdx.x * 256 + threadIdx.x;
  size_t base = (size_t)t * 4;
  float4 v = *reinterpret_cast<const float4*>(W + base);
  float am = fmaxf(fmaxf(fabsf(v.x), fabsf(v.y)), fmaxf(fabsf(v.z), fabsf(v.w)));
  am = fmaxf(am, __shfl_xor(am, 1));
  am = fmaxf(am, __shfl_xor(am, 2));
  am = fmaxf(am, __shfl_xor(am, 4));
  am = fmaxf(am, __shfl_xor(am, 8));
  float d = fmaxf(am, 1e-12f);
  ushort4 o;
  o.x = f2bf(fp4_rt(v.x, d, am));
  o.y = f2bf(fp4_rt(v.y, d, am));
  o.z = f2bf(fp4_rt(v.z, d, am));
  o.w = f2bf(fp4_rt(v.w, d, am));
  *reinterpret_cast<ushort4*>(Wq + base) = o;
}

// ---------------- Kernel 2: cast x fp32 -> bf16 ----------------
__device__ __forceinline__ uint32_t pack2(float lo, float hi) {
  return (uint32_t)f2bf(lo) | ((uint32_t)f2bf(hi) << 16);
}

__global__ void cast_bf16_kernel(const float* __restrict__ X,
                                 uint32_t* __restrict__ Y) {
  int t = blockIdx.x * 256 + threadIdx.x;
  size_t base = (size_t)t * 8;
  float4 a = *reinterpret_cast<const float4*>(X + base);
  float4 b = *reinterpret_cast<const float4*>(X + base + 4);
  uint4 o;
  o.x = pack2(a.x, a.y);
  o.y = pack2(a.z, a.w);
  o.z = pack2(b.x, b.y);
  o.w = pack2(b.z, b.w);
  *reinterpret_cast<uint4*>(Y + (size_t)t * 4) = o;
}

// ---------------- Kernel 3: 256x256 8-phase PIPELINED bf16 GEMM -------------
// C[M,N] = A[M,K] * B[N,K]^T + bias.  BM=BN=256, BK=64, 512 thr = 8 waves
// (2M x 4N), acc[8][4].  LDS 128KB: [2 dbuf][A0,A1,B0,B1][16KB half].
// Register-pipelined: phase p issues ds_reads for phase p+1 into ping-pong
// frag banks (afA/afB per phase, bfA/bfB per 2 phases), waits COUNTED
// lgkmcnt(n_p), MFMAs on phase-p frags. One s_barrier per phase.
// Staging schedule (hazard rule: stage-to-half q >= last-read-issue p + 2):
//   ph0: B(1,1,2i+1)  ph1: A(1,0/1,2i+1)  ph2: -       [END2: vmcnt0+bar]
//   ph3: B(0,0,t2)    ph4: B(0,1,t2)      ph5: A(0,0/1,t2)  ph6: -
//   [END6: vmcnt0+bar]  ph7: B(1,0,t3)
// Full 3-bit LDS swizzle (0 bank conflicts, proven r4): phys = row*128 +
// (colbyte ^ ((row&7)<<4)); linear gload_lds dest + inverse-swizzled source.
#define GLOAD(src, dst)                                                        \
  __builtin_amdgcn_global_load_lds(                                           \
      (const __attribute__((address_space(1))) void*)(src),                   \
      (__attribute__((address_space(3))) void*)(dst), 16, 0, 0)

#define WAIT_LGKM4()                                                           \
  asm volatile("s_waitcnt lgkmcnt(4)" ::: "memory");                           \
  __builtin_amdgcn_sched_barrier(0);                                           \
  __builtin_amdgcn_s_setprio(1);

#define WAIT_LGKM8()                                                           \
  asm volatile("s_waitcnt lgkmcnt(8)" ::: "memory");                           \
  __builtin_amdgcn_sched_barrier(0);                                           \
  __builtin_amdgcn_s_setprio(1);

#define ENDBAR()                                                               \
  __builtin_amdgcn_s_setprio(0);                                               \
  __builtin_amdgcn_sched_barrier(0);                                           \
  __builtin_amdgcn_s_barrier();

#define ENDBAR_VM0()                                                           \
  __builtin_amdgcn_s_setprio(0);                                               \
  __builtin_amdgcn_sched_barrier(0);                                           \
  asm volatile("s_waitcnt vmcnt(0)" ::: "memory");                             \
  __builtin_amdgcn_s_barrier();

__global__ __launch_bounds__(512, 2) void gemm256_kernel(
    const short* __restrict__ A, const short* __restrict__ B,
    const float* __restrict__ bias, float* __restrict__ C) {
  __shared__ short lds[2][4][8192];  // [buf][A0,A1,B0,B1][16KB half]

  const int tid = threadIdx.x;
  const int wave = tid >> 6;
  const int lane = tid & 63;
  const int l15 = lane & 15;
  const int q4 = lane >> 4;
  const int wm = wave >> 2;  // 0..1
  const int wn = wave & 3;   // 0..3

  // XCD-chunked swizzle: 1376 blocks = 8 XCDs x 172
  const int bid = blockIdx.x;
  const int g = bid & 7;
  const int idx = bid >> 3;  // 0..171
  const int brow = (g * 4 + (idx & 3)) * 256;
  const int bcol = (idx >> 2) * 256;

  // staging source (inverse-swizzled global addr; linear LDS dest)
  const int srow = tid >> 3;                             // 0..63
  const int scol = ((tid & 7) ^ ((tid >> 3) & 7)) << 3;  // element col
  const short* Asrc = A + (size_t)(brow + srow) * K_DIM + scol;
  const short* Bsrc = B + (size_t)(bcol + srow) * K_DIM + scol;
  const int wu0 = wave * 512;
  const int wu1 = 4096 + wave * 512;

  auto stageA = [&](int buf, int half, int t) {
    const short* s = Asrc + (size_t)half * 128 * K_DIM + t * 64;
    GLOAD(s, &lds[buf][half][wu0]);
    GLOAD(s + (size_t)64 * K_DIM, &lds[buf][half][wu1]);
  };
  auto stageB = [&](int buf, int half, int t) {
    const short* s = Bsrc + (size_t)half * 128 * K_DIM + t * 64;
    GLOAD(s, &lds[buf][2 + half][wu0]);
    GLOAD(s + (size_t)64 * K_DIM, &lds[buf][2 + half][wu1]);
  };

  // fragment read bases (swizzled): frag(m,kk) phys byte =
  //   (m*16+l15)*128 + (((kk<<2|q4) ^ (l15&7)) << 4)
  const int offk0 = ((q4 ^ (l15 & 7)) << 4);
  const int offk1 = offk0 ^ 64;
  const char* aP[2] = {(const char*)&lds[0][wm][0] + l15 * 128,
                       (const char*)&lds[1][wm][0] + l15 * 128};
  const char* bP[2] = {
      (const char*)&lds[0][2 + (wn >> 1)][0] + (wn & 1) * 8192 + l15 * 128,
      (const char*)&lds[1][2 + (wn >> 1)][0] + (wn & 1) * 8192 + l15 * 128};

  f32x4 acc[8][4] = {};
  bf16x8 afA[4], afB[4], bfA[4], bfB[4];

  // ---- prologue: stage buf0 (tile0, 4 halves) + B(1,0, tile1) ----
  stageB(0, 0, 0);
  stageB(0, 1, 0);
  stageA(0, 0, 0);
  stageA(0, 1, 0);
  stageB(1, 0, 1);
  asm volatile("s_waitcnt vmcnt(2)" ::: "memory");  // buf0's 8 loads landed
  __builtin_amdgcn_s_barrier();
  // prologue reads: S0 = buf0.A m0-3 kk0 + buf0.B kk0
#pragma unroll
  for (int m = 0; m < 4; ++m) afA[m] = *(const bf16x8*)(aP[0] + m * 2048 + offk0);
#pragma unroll
  for (int n = 0; n < 4; ++n) bfA[n] = *(const bf16x8*)(bP[0] + n * 2048 + offk0);

  for (int i = 0; i < 32; ++i) {
    const int t1 = 2 * i + 1;
    const int t2 = (2 * i + 2 < 64) ? 2 * i + 2 : 63;  // clamped tail (dead data)
    const int t3 = (2 * i + 3 < 64) ? 2 * i + 3 : 63;

    // ph0: read S1 (buf0.A m4-7 kk0); stage B(1,1,t1); MFMA Q0 = afA x bfA
#pragma unroll
    for (int m = 0; m < 4; ++m)
      afB[m] = *(const bf16x8*)(aP[0] + (4 + m) * 2048 + offk0);
    stageB(1, 1, t1);
    WAIT_LGKM4();
#pragma unroll
    for (int m = 0; m < 4; ++m)
#pragma unroll
      for (int n = 0; n < 4; ++n)
        acc[m][n] = __builtin_amdgcn_mfma_f32_16x16x32_bf16(afA[m], bfA[n],
                                                            acc[m][n], 0, 0, 0);
    ENDBAR();

    // ph1: read S2 (buf0.A m0-3 kk1 + buf0.B kk1); stage A(1,*,t1); Q1 = afB x bfA
#pragma unroll
    for (int m = 0; m < 4; ++m)
      afA[m] = *(const bf16x8*)(aP[0] + m * 2048 + offk1);
#pragma unroll
    for (int n = 0; n < 4; ++n)
      bfB[n] = *(const bf16x8*)(bP[0] + n * 2048 + offk1);
    stageA(1, 0, t1);
    stageA(1, 1, t1);
    WAIT_LGKM8();
#pragma unroll
    for (int m = 0; m < 4; ++m)
#pragma unroll
      for (int n = 0; n < 4; ++n)
        acc[4 + m][n] = __builtin_amdgcn_mfma_f32_16x16x32_bf16(
            afB[m], bfA[n], acc[4 + m][n], 0, 0, 0);
    ENDBAR();

    // ph2: read S3 (buf0.A m4-7 kk1); Q2 = afA x bfB; END: vmcnt(0) [buf1 ready]
#pragma unroll
    for (int m = 0; m < 4; ++m)
      afB[m] = *(const bf16x8*)(aP[0] + (4 + m) * 2048 + offk1);
    WAIT_LGKM4();
#pragma unroll
    for (int m = 0; m < 4; ++m)
#pragma unroll
      for (int n = 0; n < 4; ++n)
        acc[m][n] = __builtin_amdgcn_mfma_f32_16x16x32_bf16(afA[m], bfB[n],
                                                            acc[m][n], 0, 0, 0);
    ENDBAR_VM0();

    // ph3: read S4 (buf1.A m0-3 kk0 + buf1.B kk0); stage B(0,0,t2); Q3 = afB x bfB
#pragma unroll
    for (int m = 0; m < 4; ++m)
      afA[m] = *(const bf16x8*)(aP[1] + m * 2048 + offk0);
#pragma unroll
    for (int n = 0; n < 4; ++n)
      bfA[n] = *(const bf16x8*)(bP[1] + n * 2048 + offk0);
    stageB(0, 0, t2);
    WAIT_LGKM8();
#pragma unroll
    for (int m = 0; m < 4; ++m)
#pragma unroll
      for (int n = 0; n < 4; ++n)
        acc[4 + m][n] = __builtin_amdgcn_mfma_f32_16x16x32_bf16(
            afB[m], bfB[n], acc[4 + m][n], 0, 0, 0);
    ENDBAR();

    // ph4: read S5 (buf1.A m4-7 kk0); stage B(0,1,t2); Q0' = afA x bfA
#pragma unroll
    for (int m = 0; m < 4; ++m)
      afB[m] = *(const bf16x8*)(aP[1] + (4 + m) * 2048 + offk0);
    stageB(0, 1, t2);
    WAIT_LGKM4();
#pragma unroll
    for (int m = 0; m < 4; ++m)
#pragma unroll
      for (int n = 0; n < 4; ++n)
        acc[m][n] = __builtin_amdgcn_mfma_f32_16x16x32_bf16(afA[m], bfA[n],
                                                            acc[m][n], 0, 0, 0);
    ENDBAR();

    // ph5: read S6 (buf1.A m0-3 kk1 + buf1.B kk1); stage A(0,*,t2); Q1' = afB x bfA
#pragma unroll
    for (int m = 0; m < 4; ++m)
      afA[m] = *(const bf16x8*)(aP[1] + m * 2048 + offk1);
#pragma unroll
    for (int n = 0; n < 4; ++n)
      bfB[n] = *(const bf16x8*)(bP[1] + n * 2048 + offk1);
    stageA(0, 0, t2);
    stageA(0, 1, t2);
    WAIT_LGKM8();
#pragma unroll
    for (int m = 0; m < 4; ++m)
#pragma unroll
      for (int n = 0; n < 4; ++n)
        acc[4 + m][n] = __builtin_amdgcn_mfma_f32_16x16x32_bf16(
            afB[m], bfA[n], acc[4 + m][n], 0, 0, 0);
    ENDBAR();

    // ph6: read S7 (buf1.A m4-7 kk1); Q2' = afA x bfB; END: vmcnt(0) [buf0' ready]
#pragma unroll
    for (int m = 0; m < 4; ++m)
      afB[m] = *(const bf16x8*)(aP[1] + (4 + m) * 2048 + offk1);
    WAIT_LGKM4();
#pragma unroll
    for (int m = 0; m < 4; ++m)
#pragma unroll
      for (int n = 0; n < 4; ++n)
        acc[m][n] = __builtin_amdgcn_mfma_f32_16x16x32_bf16(afA[m], bfB[n],
                                                            acc[m][n], 0, 0, 0);
    ENDBAR_VM0();

    // ph7: read S0' (buf0.A m0-3 kk0 + buf0.B kk0, NEW tile t2); stage B(1,0,t3);
    //      Q3' = afB x bfB
#pragma unroll
    for (int m = 0; m < 4; ++m)
      afA[m] = *(const bf16x8*)(aP[0] + m * 2048 + offk0);
#pragma unroll
    for (int n = 0; n < 4; ++n)
      bfA[n] = *(const bf16x8*)(bP[0] + n * 2048 + offk0);
    stageB(1, 0, t3);
    WAIT_LGKM8();
#pragma unroll
    for (int m = 0; m < 4; ++m)
#pragma unroll
      for (int n = 0; n < 4; ++n)
        acc[4 + m][n] = __builtin_amdgcn_mfma_f32_16x16x32_bf16(
            afB[m], bfB[n], acc[4 + m][n], 0, 0, 0);
    ENDBAR();
  }

  // ---- epilogue: C/D layout col=lane&15, row=(lane>>4)*4+j ----
  const int crow0 = brow + wm * 128 + q4 * 4;
  const int ccol0 = bcol + wn * 64 + l15;
#pragma unroll
  for (int n = 0; n < 4; ++n) {
    const float bv = bias[ccol0 + n * 16];
#pragma unroll
    for (int m = 0; m < 8; ++m) {
      const size_t rb = (size_t)(crow0 + m * 16) * N_DIM + (ccol0 + n * 16);
#pragma unroll
      for (int j = 0; j < 4; ++j) C[rb + (size_t)j * N_DIM] = acc[m][n][j] + bv;
    }
  }
}

extern "C" void kernel_launch(void* const* d_in, const int* in_sizes, int n_in,
                              void* d_out, int out_size, void* d_ws, size_t ws_size,
                              hipStream_t stream) {
  const float* x = (const float*)d_in[0];     // [8192, 4096]
  const float* w = (const float*)d_in[1];     // [11008, 4096]
  const float* bias = (const float*)d_in[2];  // [11008]
  float* out = (float*)d_out;                 // [8192, 11008]

  unsigned short* wq = (unsigned short*)d_ws;       // N*K bf16
  unsigned short* xb = wq + (size_t)N_DIM * K_DIM;  // M*K bf16

  {
    int nt = N_DIM * K_DIM / 4;
    quant_fp4_kernel<<<nt / 256, 256, 0, stream>>>(w, wq);
  }
  {
    int nt = M_DIM * K_DIM / 8;
    cast_bf16_kernel<<<nt / 256, 256, 0, stream>>>(x, (uint32_t*)xb);
  }
  {
    // 1376 = (8192/256) * (11008/256) = 8 XCD-chunks x 172
    gemm256_kernel<<<dim3(1376), 512, 0, stream>>>((const short*)xb,
                                                   (const short*)wq, bias, out);
  }
}